// Round 5
// baseline (688.143 us; speedup 1.0000x reference)
//
#include <hip/hip_runtime.h>

#define NN_ 4096
#define IN_DIM_ 512
#define D_ 256
#define OUT_ 128
#define NB 256          // grid: 1 block per CU
#define BT 512          // 8 waves per block

typedef unsigned short u16;
typedef unsigned int u32;
typedef __attribute__((ext_vector_type(8))) short short8;
typedef __attribute__((ext_vector_type(4))) float f32x4;

union U16x8 { uint4 u4; short8 s8; };

__device__ __forceinline__ u16 f2bf(float f){
  u32 u = __builtin_bit_cast(u32, f);
  u = (u + 0x7FFFu + ((u >> 16) & 1u)) >> 16;
  return (u16)u;
}
__device__ __forceinline__ float bf2f(u16 u){ return __builtin_bit_cast(float, ((u32)u) << 16); }
__device__ __forceinline__ float sigm(float v){ return 1.f / (1.f + __expf(-v)); }

struct Params {
  const float *x, *lin1_w, *lin1_b, *gat_W, *a_self, *a_nei, *W_ih, *lin2_w, *lin2_b;
  const int *adj;
  float *A_pred, *z_out, *out_o;
  u16 *x_bf, *h_bf, *g_bf, *h1_bf, *zb, *Wih_bf, *WcT_bf, *l2w_bf;
  float *bcomb, *s, *t;
  int *bar;
};

// ---- device-scope global barrier: monotonic epoch counter, all blocks resident
__device__ __forceinline__ void gsync(int* bar, int epoch) {
  __threadfence();                       // release my block's global writes
  __syncthreads();
  if (threadIdx.x == 0) {
    __hip_atomic_fetch_add(bar, 1, __ATOMIC_ACQ_REL, __HIP_MEMORY_SCOPE_AGENT);
    while (__hip_atomic_load(bar, __ATOMIC_ACQUIRE, __HIP_MEMORY_SCOPE_AGENT) < epoch * NB) {}
  }
  __syncthreads();
  __threadfence();                       // acquire: invalidate stale cached lines
}

// -------- attn for one row, executed by a 256-thread half in lockstep --------
__device__ __forceinline__ void attn_row(const Params& P, int row, int lt,
                                         int lane, int wv, char* SM) {
  int* nidx   = (int*)SM;                       // [512]
  float* ne   = (float*)(SM + 2048);            // [512]
  float (*red)[256] = (float(*)[256])(SM + 4096);
  int* wtot   = (int*)(SM + 8192);
  float* redm = (float*)(SM + 8208);
  float* reds = (float*)(SM + 8224);
  const int4* arow = (const int4*)(P.adj + (size_t)row * NN_);
  int4 a4[4];
  #pragma unroll
  for (int i = 0; i < 4; i++) a4[i] = arow[(i << 8) + lt];
  int vals[16] = {a4[0].x, a4[0].y, a4[0].z, a4[0].w, a4[1].x, a4[1].y, a4[1].z, a4[1].w,
                  a4[2].x, a4[2].y, a4[2].z, a4[2].w, a4[3].x, a4[3].y, a4[3].z, a4[3].w};
  int c = 0;
  #pragma unroll
  for (int q = 0; q < 16; q++) c += (vals[q] > 0);
  int pref = c;
  #pragma unroll
  for (int off = 1; off < 64; off <<= 1) {
    int u = __shfl_up(pref, off);
    if (lane >= off) pref += u;
  }
  if (lane == 63) wtot[wv] = pref;
  __syncthreads();                               // B1
  int woff = 0;
  #pragma unroll
  for (int w = 0; w < 4; w++) woff += (w < wv) ? wtot[w] : 0;
  int n = wtot[0] + wtot[1] + wtot[2] + wtot[3];
  float si = P.s[row];
  int p = woff + pref - c;
  #pragma unroll
  for (int i = 0; i < 4; i++)
    #pragma unroll
    for (int q = 0; q < 4; q++) {
      if (vals[(i << 2) + q] > 0) {
        int j = (i << 10) + (lt << 2) + q;
        float e = 0.2f * (si + P.t[j]);
        e = e > 0.f ? e : 0.2f * e;
        if (p < 512) { nidx[p] = j; ne[p] = e; }
        p++;
      }
    }
  if (n > 512) n = 512;
  __syncthreads();                               // B2
  float lm = -3.0e38f;
  if (lt < n) lm = ne[lt];
  if (lt + 256 < n) lm = fmaxf(lm, ne[lt + 256]);
  #pragma unroll
  for (int off = 32; off; off >>= 1) lm = fmaxf(lm, __shfl_xor(lm, off));
  if (lane == 0) redm[wv] = lm;
  __syncthreads();                               // B3
  float m = fmaxf(fmaxf(redm[0], redm[1]), fmaxf(redm[2], redm[3]));
  float ls = 0.f;
  if (lt < n)       { float w0 = __expf(ne[lt] - m);       ne[lt] = w0;       ls += w0; }
  if (lt + 256 < n) { float w1 = __expf(ne[lt + 256] - m); ne[lt + 256] = w1; ls += w1; }
  #pragma unroll
  for (int off = 32; off; off >>= 1) ls += __shfl_xor(ls, off);
  if (lane == 0) reds[wv] = ls;
  __syncthreads();                               // B4
  float S = reds[0] + reds[1] + reds[2] + reds[3];
  const int hl = lane & 31, ksel = lane >> 5;
  float acc[8] = {0.f, 0.f, 0.f, 0.f, 0.f, 0.f, 0.f, 0.f};
  for (int k = (wv << 1) + ksel; k < n; k += 8) {
    float wgt = ne[k];
    int j = nidx[k];
    U16x8 hv; hv.u4 = *(const uint4*)(P.h_bf + ((size_t)j << 8) + (hl << 3));
    #pragma unroll
    for (int q = 0; q < 8; q++)
      acc[q] = __builtin_fmaf(wgt, bf2f((u16)hv.s8[q]), acc[q]);
  }
  #pragma unroll
  for (int q = 0; q < 8; q++) acc[q] += __shfl_down(acc[q], 32);
  if (lane < 32) {
    #pragma unroll
    for (int q = 0; q < 8; q++) red[wv][(hl << 3) + q] = acc[q];
  }
  __syncthreads();                               // B5
  float hp;
  if (n > 0) {
    hp = (red[0][lt] + red[1][lt] + red[2][lt] + red[3][lt]) / S;
  } else {
    float a2 = 0.f;
    for (int j = 0; j < NN_; j++) a2 += bf2f(P.h_bf[((size_t)j << 8) + lt]);
    hp = a2 / NN_;
  }
  float el = hp > 0.f ? hp : __expf(hp) - 1.f;
  P.g_bf[((size_t)row << 8) + lt] = f2bf(tanhf(el));
}

__global__ __launch_bounds__(BT, 2) void mega(Params P) {
  __shared__ __align__(16) char SMEM[32768];
  uint4* As = (uint4*)SMEM;            // up to 1024 entries (16 KB)
  uint4* Bs = (uint4*)(SMEM + 16384);  // up to 1024 entries (16 KB)
  const int tid = threadIdx.x;
  const int bid = blockIdx.x;
  const int wave = tid >> 6, lane = tid & 63;
  const int r16 = lane & 15, kg = lane >> 4;

  // ================= P0: prep (converts + Wcomb + bcomb) =================
  for (int u = bid; u < 1201; u += NB) {
    if (u < 1024) {                       // x fp32 -> bf16
      int off = u * 2048 + tid * 4;
      float4 v = *(const float4*)(P.x + off);
      ushort4 o = {f2bf(v.x), f2bf(v.y), f2bf(v.z), f2bf(v.w)};
      *(ushort4*)(P.x_bf + off) = o;
    } else if (u < 1152) {                // W_ih permuted -> bf16
      int r = ((u - 1024) << 3) + (tid >> 6);
      int grp = r >> 6, gate = (r >> 4) & 3, hcl = r & 15;
      int orig = gate * 256 + grp * 16 + hcl;
      int k = (lane) << 2;
      float4 v = *(const float4*)(P.W_ih + (size_t)orig * 256 + k);
      ushort4 o = {f2bf(v.x), f2bf(v.y), f2bf(v.z), f2bf(v.w)};
      *(ushort4*)(P.Wih_bf + (size_t)r * 256 + k) = o;
    } else if (u < 1168) {                // lin2_w -> bf16
      int off = (u - 1152) * 2048 + tid * 4;
      float4 v = *(const float4*)(P.lin2_w + off);
      ushort4 o = {f2bf(v.x), f2bf(v.y), f2bf(v.z), f2bf(v.w)};
      *(ushort4*)(P.l2w_bf + off) = o;
    } else if (u < 1200) {                // Wcomb = lin1_w^T @ gat_W (fp32)
      float (*Af)[68] = (float(*)[68])SMEM;
      float (*Bf)[68] = (float(*)[68])(SMEM + 8704);
      int local = u - 1168;
      int m0 = (local & 7) << 6, n0 = (local >> 3) << 6;
      const int tx = tid & 15, ty = (tid >> 4) & 15;
      float acc[4][4] = {};
      for (int k0 = 0; k0 < 256; k0 += 32) {
        int kk = tid >> 4, c4 = (tid & 15) << 2;
        *(float4*)&Af[kk][c4] = *(const float4*)(P.lin1_w + (size_t)(k0 + kk) * 512 + m0 + c4);
        *(float4*)&Bf[kk][c4] = *(const float4*)(P.gat_W + (size_t)(k0 + kk) * 256 + n0 + c4);
        __syncthreads();
        if (tid < 256) {
          #pragma unroll
          for (int kx = 0; kx < 32; kx++) {
            float4 av = *(const float4*)&Af[kx][ty << 2];
            float4 bv = *(const float4*)&Bf[kx][tx << 2];
            float a_[4] = {av.x, av.y, av.z, av.w};
            float b_[4] = {bv.x, bv.y, bv.z, bv.w};
            #pragma unroll
            for (int r = 0; r < 4; r++)
              #pragma unroll
              for (int c = 0; c < 4; c++)
                acc[r][c] = __builtin_fmaf(a_[r], b_[c], acc[r][c]);
          }
        }
        __syncthreads();
      }
      if (tid < 256) {
        #pragma unroll
        for (int r = 0; r < 4; r++)
          #pragma unroll
          for (int c = 0; c < 4; c++)
            P.WcT_bf[(size_t)(n0 + (tx << 2) + c) * 512 + m0 + (ty << 2) + r] = f2bf(acc[r][c]);
      }
    } else {                              // bcomb
      if (tid < 256) {
        float a = 0.f;
        #pragma unroll 8
        for (int d = 0; d < 256; d++)
          a = __builtin_fmaf(P.lin1_b[d], P.gat_W[(size_t)d * 256 + tid], a);
        P.bcomb[tid] = a;
      }
    }
  }
  gsync(P.bar, 1);

  // ====== P1: h = x @ Wcomb + bcomb -> bf16. 256 tiles of 64x64, K=512 ======
  {
    const int row0 = (bid >> 2) << 6, col0 = (bid & 3) << 6;
    const int wm = wave >> 1, wn = wave & 1;   // 4x2 waves: 16 rows x 32 cols
    f32x4 acc[2];
    acc[0] = (f32x4){0.f,0.f,0.f,0.f}; acc[1] = (f32x4){0.f,0.f,0.f,0.f};
    for (int k0 = 0; k0 < IN_DIM_; k0 += 64) {
      int r = tid >> 3, cc = tid & 7;
      As[(r << 3) + (cc ^ (r & 7))] = *(const uint4*)(P.x_bf + (size_t)(row0 + r) * IN_DIM_ + k0 + cc * 8);
      Bs[(r << 3) + (cc ^ (r & 7))] = *(const uint4*)(P.WcT_bf + (size_t)(col0 + r) * IN_DIM_ + k0 + cc * 8);
      __syncthreads();
      #pragma unroll
      for (int ks = 0; ks < 2; ks++) {
        int kb = (ks << 2) + kg;
        U16x8 a, b[2];
        int ra = (wm << 4) + r16;
        a.u4 = As[(ra << 3) + (kb ^ (ra & 7))];
        #pragma unroll
        for (int n2 = 0; n2 < 2; n2++) {
          int rb = (wn << 5) + (n2 << 4) + r16;
          b[n2].u4 = Bs[(rb << 3) + (kb ^ (rb & 7))];
        }
        #pragma unroll
        for (int n2 = 0; n2 < 2; n2++)
          acc[n2] = __builtin_amdgcn_mfma_f32_16x16x32_bf16(a.s8, b[n2].s8, acc[n2], 0, 0, 0);
      }
      __syncthreads();
    }
    #pragma unroll
    for (int n2 = 0; n2 < 2; n2++)
      #pragma unroll
      for (int q = 0; q < 4; q++) {
        size_t gr = row0 + (wm << 4) + (kg << 2) + q;
        int gc = col0 + (wn << 5) + (n2 << 4) + r16;
        P.h_bf[gr * D_ + gc] = f2bf(acc[n2][q] + P.bcomb[gc]);
      }
  }
  gsync(P.bar, 2);

  // ================= P2: s/t row dots =================
  for (int u = bid; u < 512; u += NB) {
    int row = (u << 3) + wave;
    U16x8 hv; hv.u4 = *(const uint4*)(P.h_bf + ((size_t)row << 8) + (lane << 3));
    float4 a0 = *(const float4*)(P.a_self + lane * 8);
    float4 a1 = *(const float4*)(P.a_self + lane * 8 + 4);
    float4 b0 = *(const float4*)(P.a_nei + lane * 8);
    float4 b1 = *(const float4*)(P.a_nei + lane * 8 + 4);
    float av[8] = {a0.x, a0.y, a0.z, a0.w, a1.x, a1.y, a1.z, a1.w};
    float bv[8] = {b0.x, b0.y, b0.z, b0.w, b1.x, b1.y, b1.z, b1.w};
    float ds = 0.f, dn = 0.f;
    #pragma unroll
    for (int q = 0; q < 8; q++) {
      float hf = bf2f((u16)hv.s8[q]);
      ds = __builtin_fmaf(hf, av[q], ds);
      dn = __builtin_fmaf(hf, bv[q], dn);
    }
    #pragma unroll
    for (int off = 32; off; off >>= 1) { ds += __shfl_down(ds, off); dn += __shfl_down(dn, off); }
    if (lane == 0) { P.s[row] = ds; P.t[row] = dn; }
  }
  gsync(P.bar, 3);

  // ===== P3: masked softmax + gather + tanh(elu): 2 rows/block (halves) =====
  {
    const int half = tid >> 8, lt = tid & 255, wv = lt >> 6;
    char* SM = SMEM + half * 12288;
    for (int pr = bid; pr < 2048; pr += NB)
      attn_row(P, (pr << 1) + half, lt, lane, wv, SM);
  }
  gsync(P.bar, 4);

  // ====== P4: gates GEMM (permuted Wih) + LSTM. 256 tiles 128x128, K=256 =====
  {
    const int bx = bid & 7, by = bid >> 3;
    const int row0 = by << 7, col0 = bx << 7;
    const int wm = wave >> 1, wn = wave & 1;   // 4x2: 32 rows x 64 cols
    f32x4 acc[2][4];
    #pragma unroll
    for (int m2 = 0; m2 < 2; m2++)
      #pragma unroll
      for (int n2 = 0; n2 < 4; n2++) acc[m2][n2] = (f32x4){0.f,0.f,0.f,0.f};
    for (int k0 = 0; k0 < D_; k0 += 64) {
      #pragma unroll
      for (int i = 0; i < 2; i++) {
        int id = tid + (i << 9);
        int r = id >> 3, cc = id & 7;
        As[(r << 3) + (cc ^ (r & 7))] = *(const uint4*)(P.g_bf + (size_t)(row0 + r) * D_ + k0 + cc * 8);
        Bs[(r << 3) + (cc ^ (r & 7))] = *(const uint4*)(P.Wih_bf + (size_t)(col0 + r) * D_ + k0 + cc * 8);
      }
      __syncthreads();
      #pragma unroll
      for (int ks = 0; ks < 2; ks++) {
        int kb = (ks << 2) + kg;
        U16x8 a[2], b[4];
        #pragma unroll
        for (int m2 = 0; m2 < 2; m2++) {
          int ra = (wm << 5) + (m2 << 4) + r16;
          a[m2].u4 = As[(ra << 3) + (kb ^ (ra & 7))];
        }
        #pragma unroll
        for (int n2 = 0; n2 < 4; n2++) {
          int rb = (wn << 6) + (n2 << 4) + r16;
          b[n2].u4 = Bs[(rb << 3) + (kb ^ (rb & 7))];
        }
        #pragma unroll
        for (int m2 = 0; m2 < 2; m2++)
          #pragma unroll
          for (int n2 = 0; n2 < 4; n2++)
            acc[m2][n2] = __builtin_amdgcn_mfma_f32_16x16x32_bf16(
                a[m2].s8, b[n2].s8, acc[m2][n2], 0, 0, 0);
      }
      __syncthreads();
    }
    const int grp = (bx << 1) + wn;
    const int hc = (grp << 4) + r16;
    #pragma unroll
    for (int m2 = 0; m2 < 2; m2++)
      #pragma unroll
      for (int q = 0; q < 4; q++) {
        size_t grow = row0 + (wm << 5) + (m2 << 4) + (kg << 2) + q;
        float ig = acc[m2][0][q], gg = acc[m2][2][q], og = acc[m2][3][q];
        float c1 = sigm(ig) * tanhf(gg);
        P.h1_bf[grow * D_ + hc] = f2bf(sigm(og) * tanhf(c1));
      }
  }
  gsync(P.bar, 5);

  // ====== P5: lin2 + bias + L2-normalize. 32 blocks of 128 rows, K=256 ======
  if (bid < 32) {
    const int row0 = bid << 7;
    f32x4 acc[8];
    #pragma unroll
    for (int n2 = 0; n2 < 8; n2++) acc[n2] = (f32x4){0.f,0.f,0.f,0.f};
    for (int k0 = 0; k0 < D_; k0 += 64) {
      #pragma unroll
      for (int i = 0; i < 2; i++) {
        int id = tid + (i << 9);
        int r = id >> 3, cc = id & 7;
        As[(r << 3) + (cc ^ (r & 7))] = *(const uint4*)(P.h1_bf + (size_t)(row0 + r) * D_ + k0 + cc * 8);
        Bs[(r << 3) + (cc ^ (r & 7))] = *(const uint4*)(P.l2w_bf + (size_t)r * D_ + k0 + cc * 8);
      }
      __syncthreads();
      #pragma unroll
      for (int ks = 0; ks < 2; ks++) {
        int kb = (ks << 2) + kg;
        U16x8 a, b[8];
        int ra = (wave << 4) + r16;
        a.u4 = As[(ra << 3) + (kb ^ (ra & 7))];
        #pragma unroll
        for (int n2 = 0; n2 < 8; n2++) {
          int rb = (n2 << 4) + r16;
          b[n2].u4 = Bs[(rb << 3) + (kb ^ (rb & 7))];
        }
        #pragma unroll
        for (int n2 = 0; n2 < 8; n2++)
          acc[n2] = __builtin_amdgcn_mfma_f32_16x16x32_bf16(a.s8, b[n2].s8, acc[n2], 0, 0, 0);
      }
      __syncthreads();
    }
    #pragma unroll
    for (int q = 0; q < 4; q++) {
      size_t grow = row0 + (wave << 4) + (kg << 2) + q;
      float v[8]; float ss = 0.f;
      #pragma unroll
      for (int n2 = 0; n2 < 8; n2++) {
        float vv = acc[n2][q] + P.lin2_b[(n2 << 4) + r16];
        v[n2] = vv; ss = __builtin_fmaf(vv, vv, ss);
      }
      ss += __shfl_xor(ss, 1); ss += __shfl_xor(ss, 2);
      ss += __shfl_xor(ss, 4); ss += __shfl_xor(ss, 8);
      float inv = 1.f / fmaxf(sqrtf(ss), 1e-12f);
      #pragma unroll
      for (int n2 = 0; n2 < 8; n2++) {
        int gc = (n2 << 4) + r16;
        float vv = v[n2], zz = vv * inv;
        P.out_o[grow * OUT_ + gc] = vv;
        P.z_out[grow * OUT_ + gc] = zz;
        P.zb[grow * OUT_ + gc] = f2bf(zz);
      }
    }
  }
  gsync(P.bar, 6);

  // ====== P6: decode A_pred = sigmoid(z z^T). 1024 tiles 128x128, K=128 ======
  for (int u = bid; u < 1024; u += NB) {
    const int by = u >> 5, bx = u & 31;
    const int row0 = by << 7, col0 = bx << 7;
    const int wm = wave >> 2, wn = wave & 3;   // 2x4: 64 rows x 32 cols
    f32x4 acc[4][2];
    #pragma unroll
    for (int m2 = 0; m2 < 4; m2++)
      #pragma unroll
      for (int n2 = 0; n2 < 2; n2++) acc[m2][n2] = (f32x4){0.f,0.f,0.f,0.f};
    for (int k0 = 0; k0 < OUT_; k0 += 64) {
      #pragma unroll
      for (int i = 0; i < 2; i++) {
        int id = tid + (i << 9);
        int r = id >> 3, cc = id & 7;
        As[(r << 3) + (cc ^ (r & 7))] = *(const uint4*)(P.zb + (size_t)(row0 + r) * OUT_ + k0 + cc * 8);
        Bs[(r << 3) + (cc ^ (r & 7))] = *(const uint4*)(P.zb + (size_t)(col0 + r) * OUT_ + k0 + cc * 8);
      }
      __syncthreads();
      #pragma unroll
      for (int ks = 0; ks < 2; ks++) {
        int kb = (ks << 2) + kg;
        U16x8 a[4], b[2];
        #pragma unroll
        for (int m2 = 0; m2 < 4; m2++) {
          int ra = (wm << 6) + (m2 << 4) + r16;
          a[m2].u4 = As[(ra << 3) + (kb ^ (ra & 7))];
        }
        #pragma unroll
        for (int n2 = 0; n2 < 2; n2++) {
          int rb = (wn << 5) + (n2 << 4) + r16;
          b[n2].u4 = Bs[(rb << 3) + (kb ^ (rb & 7))];
        }
        #pragma unroll
        for (int m2 = 0; m2 < 4; m2++)
          #pragma unroll
          for (int n2 = 0; n2 < 2; n2++)
            acc[m2][n2] = __builtin_amdgcn_mfma_f32_16x16x32_bf16(
                a[m2].s8, b[n2].s8, acc[m2][n2], 0, 0, 0);
      }
      __syncthreads();
    }
    #pragma unroll
    for (int m2 = 0; m2 < 4; m2++)
      #pragma unroll
      for (int n2 = 0; n2 < 2; n2++)
        #pragma unroll
        for (int q = 0; q < 4; q++) {
          size_t gr = row0 + (wm << 6) + (m2 << 4) + (kg << 2) + q;
          int gc = col0 + (wn << 5) + (n2 << 4) + r16;
          P.A_pred[gr * NN_ + gc] = sigm(acc[m2][n2][q]);
        }
  }
}

extern "C" void kernel_launch(void* const* d_in, const int* in_sizes, int n_in,
                              void* d_out, int out_size, void* d_ws, size_t ws_size,
                              hipStream_t stream) {
  Params p;
  p.x      = (const float*)d_in[0];
  p.adj    = (const int*)  d_in[1];
  p.lin1_w = (const float*)d_in[2];
  p.lin1_b = (const float*)d_in[3];
  p.gat_W  = (const float*)d_in[4];
  p.a_self = (const float*)d_in[5];
  p.a_nei  = (const float*)d_in[6];
  p.W_ih   = (const float*)d_in[7];
  p.lin2_w = (const float*)d_in[9];
  p.lin2_b = (const float*)d_in[10];

  p.A_pred = (float*)d_out;
  p.z_out  = p.A_pred + (size_t)NN_ * NN_;
  p.out_o  = p.z_out + (size_t)NN_ * OUT_;

  char* w = (char*)d_ws;
  p.x_bf   = (u16*)w;                                 // 4 MB
  p.h_bf   = (u16*)(w + (4u << 20));                  // 2 MB
  p.g_bf   = (u16*)(w + (6u << 20));                  // 2 MB
  p.h1_bf  = (u16*)(w + (8u << 20));                  // 2 MB
  p.zb     = (u16*)(w + (10u << 20));                 // 1 MB
  p.Wih_bf = (u16*)(w + (11u << 20));                 // 512 KB
  p.WcT_bf = (u16*)(w + (11u << 20) + (512u << 10));  // 256 KB
  p.l2w_bf = (u16*)(w + (11u << 20) + (768u << 10));  // 64 KB
  p.bcomb  = (float*)(w + (11u << 20) + (832u << 10));// 1 KB
  p.s      = (float*)(w + (11u << 20) + (896u << 10));// 16 KB
  p.t      = (float*)(w + (11u << 20) + (960u << 10));// 16 KB
  p.bar    = (int*)(w + (12u << 20));                 // barrier counter

  hipMemsetAsync(p.bar, 0, 256, stream);
  mega<<<dim3(NB), dim3(BT), 0, stream>>>(p);
}

// Round 7
// 103.810 us; speedup vs baseline: 6.6289x; 6.6289x over previous
//
#include <hip/hip_runtime.h>

#define NN_ 4096
#define IN_DIM_ 512
#define D_ 256
#define OUT_ 128

typedef unsigned short u16;
typedef unsigned int u32;
typedef __attribute__((ext_vector_type(8))) short short8;
typedef __attribute__((ext_vector_type(4))) float f32x4;

union U16x8 { uint4 u4; short8 s8; };

__device__ __forceinline__ u16 f2bf(float f){
  u32 u = __builtin_bit_cast(u32, f);
  u = (u + 0x7FFFu + ((u >> 16) & 1u)) >> 16;
  return (u16)u;
}
__device__ __forceinline__ float bf2f(u16 u){ return __builtin_bit_cast(float, ((u32)u) << 16); }
__device__ __forceinline__ float sigm(float v){ return 1.f / (1.f + __expf(-v)); }

// ---------- MFMA mainloop: 128x128 tile, BK=64, 4 waves (2x2), XOR-swizzle --
__device__ __forceinline__ void mfma_mainloop(const u16* __restrict__ A,
    const u16* __restrict__ B, int K, int ldA, int ldB, int row0, int col0,
    uint4* As, uint4* Bs, f32x4 acc[4][4], int tid) {
  const int wave = tid >> 6, lane = tid & 63;
  const int wm = wave >> 1, wn = wave & 1;
  const int r16 = lane & 15, kg = lane >> 4;
  for (int k0 = 0; k0 < K; k0 += 64) {
    #pragma unroll
    for (int i = 0; i < 4; i++) {
      int id = tid + (i << 8);
      int r = id >> 3, cc = id & 7;
      As[(r << 3) + (cc ^ (r & 7))] = *(const uint4*)(A + (size_t)(row0 + r) * ldA + k0 + cc * 8);
      Bs[(r << 3) + (cc ^ (r & 7))] = *(const uint4*)(B + (size_t)(col0 + r) * ldB + k0 + cc * 8);
    }
    __syncthreads();
    #pragma unroll
    for (int ks = 0; ks < 2; ks++) {
      int kb = (ks << 2) + kg;
      U16x8 a[4], b[4];
      #pragma unroll
      for (int m2 = 0; m2 < 4; m2++) {
        int r = (wm << 6) + (m2 << 4) + r16;
        a[m2].u4 = As[(r << 3) + (kb ^ (r & 7))];
      }
      #pragma unroll
      for (int n2 = 0; n2 < 4; n2++) {
        int r = (wn << 6) + (n2 << 4) + r16;
        b[n2].u4 = Bs[(r << 3) + (kb ^ (r & 7))];
      }
      #pragma unroll
      for (int m2 = 0; m2 < 4; m2++)
        #pragma unroll
        for (int n2 = 0; n2 < 4; n2++)
          acc[m2][n2] = __builtin_amdgcn_mfma_f32_16x16x32_bf16(
              a[m2].s8, b[n2].s8, acc[m2][n2], 0, 0, 0);
    }
    __syncthreads();
  }
}

// ------------- prep: Wih permute + l2w convert + Wcomb + bcomb ---------------
// blocks [0,256): Wih | [256,288): lin2_w | [288,320): Wcomb tiles | 320: bcomb
__global__ __launch_bounds__(256) void prep_kernel(
    const float* __restrict__ W_ih, const float* __restrict__ lin2_w,
    const float* __restrict__ lin1_w, const float* __restrict__ gat_W,
    const float* __restrict__ lin1_b,
    u16* __restrict__ Wih_bf, u16* __restrict__ l2w_bf,
    u16* __restrict__ WcT_bf, float* __restrict__ bcomb) {
  __shared__ __align__(16) float sh[2 * 32 * 68];
  const int b = blockIdx.x, tid = threadIdx.x;
  if (b < 256) {
    // permuted Wih: new row r -> orig = gate*256 + grp*16 + hcl
    int r = (b << 2) + (tid >> 6);
    int grp = r >> 6, gate = (r >> 4) & 3, hcl = r & 15;
    int orig = gate * 256 + grp * 16 + hcl;
    int k = (tid & 63) << 2;
    float4 v = *(const float4*)(W_ih + (size_t)orig * 256 + k);
    ushort4 o = {f2bf(v.x), f2bf(v.y), f2bf(v.z), f2bf(v.w)};
    *(ushort4*)(Wih_bf + (size_t)r * 256 + k) = o;
  } else if (b < 288) {
    int off = (b - 256) * 1024 + tid * 4;
    float4 v = *(const float4*)(lin2_w + off);
    ushort4 o = {f2bf(v.x), f2bf(v.y), f2bf(v.z), f2bf(v.w)};
    *(ushort4*)(l2w_bf + off) = o;
  } else if (b < 320) {
    // Wcomb[m][n] = sum_k lin1_w[k][m]*gat_W[k][n]; store transposed bf16
    float (*As)[68] = (float(*)[68])sh;
    float (*Bs)[68] = (float(*)[68])(sh + 32 * 68);
    int local = b - 288;
    int m0 = (local & 7) << 6, n0 = (local >> 3) << 6;
    const int tx = tid & 15, ty = tid >> 4;
    float acc[4][4] = {};
    for (int k0 = 0; k0 < 256; k0 += 32) {
      #pragma unroll
      for (int i = 0; i < 2; i++) {
        int id = tid + (i << 8);
        int kk = id >> 4, c4 = (id & 15) << 2;
        *(float4*)&As[kk][c4] = *(const float4*)(lin1_w + (size_t)(k0 + kk) * 512 + m0 + c4);
        *(float4*)&Bs[kk][c4] = *(const float4*)(gat_W + (size_t)(k0 + kk) * 256 + n0 + c4);
      }
      __syncthreads();
      #pragma unroll
      for (int kk = 0; kk < 32; kk++) {
        float4 av = *(const float4*)&As[kk][ty << 2];
        float4 bv = *(const float4*)&Bs[kk][tx << 2];
        float a_[4] = {av.x, av.y, av.z, av.w};
        float b_[4] = {bv.x, bv.y, bv.z, bv.w};
        #pragma unroll
        for (int r = 0; r < 4; r++)
          #pragma unroll
          for (int c = 0; c < 4; c++)
            acc[r][c] = __builtin_fmaf(a_[r], b_[c], acc[r][c]);
      }
      __syncthreads();
    }
    #pragma unroll
    for (int r = 0; r < 4; r++)
      #pragma unroll
      for (int c = 0; c < 4; c++)
        WcT_bf[(size_t)(n0 + (tx << 2) + c) * 512 + m0 + (ty << 2) + r] = f2bf(acc[r][c]);
  } else {
    float a = 0.f;
    #pragma unroll 8
    for (int d = 0; d < 256; d++)
      a = __builtin_fmaf(lin1_b[d], gat_W[(size_t)d * 256 + tid], a);
    bcomb[tid] = a;
  }
}

// ---- h = x @ Wcomb + bcomb -> bf16. 64x64 tiles, K=512, fp32 A staged ------
__global__ __launch_bounds__(256) void hgemm_kernel(const float* __restrict__ x,
    const u16* __restrict__ WcT, const float* __restrict__ bias,
    u16* __restrict__ h_bf) {
  __shared__ uint4 As[64 * 8];
  __shared__ uint4 Bs[64 * 8];
  const int tid = threadIdx.x;
  const int row0 = blockIdx.y << 6, col0 = blockIdx.x << 6;
  const int wave = tid >> 6, lane = tid & 63;
  const int wm = wave >> 1, wn = wave & 1;
  const int r16 = lane & 15, kg = lane >> 4;
  f32x4 acc[2][2];
  #pragma unroll
  for (int m2 = 0; m2 < 2; m2++)
    #pragma unroll
    for (int n2 = 0; n2 < 2; n2++) acc[m2][n2] = (f32x4){0.f,0.f,0.f,0.f};
  for (int k0 = 0; k0 < IN_DIM_; k0 += 64) {
    #pragma unroll
    for (int i = 0; i < 2; i++) {
      int id = tid + (i << 8);
      int r = id >> 3, cc = id & 7;
      const float* src = x + (size_t)(row0 + r) * IN_DIM_ + k0 + cc * 8;
      float4 lo = *(const float4*)src;
      float4 hi = *(const float4*)(src + 4);
      u16 e[8] = {f2bf(lo.x), f2bf(lo.y), f2bf(lo.z), f2bf(lo.w),
                  f2bf(hi.x), f2bf(hi.y), f2bf(hi.z), f2bf(hi.w)};
      As[(r << 3) + (cc ^ (r & 7))] = *(uint4*)e;
      Bs[(r << 3) + (cc ^ (r & 7))] = *(const uint4*)(WcT + (size_t)(col0 + r) * IN_DIM_ + k0 + cc * 8);
    }
    __syncthreads();
    #pragma unroll
    for (int ks = 0; ks < 2; ks++) {
      int kb = (ks << 2) + kg;
      U16x8 a[2], b[2];
      #pragma unroll
      for (int m2 = 0; m2 < 2; m2++) {
        int r = (wm << 5) + (m2 << 4) + r16;
        a[m2].u4 = As[(r << 3) + (kb ^ (r & 7))];
      }
      #pragma unroll
      for (int n2 = 0; n2 < 2; n2++) {
        int r = (wn << 5) + (n2 << 4) + r16;
        b[n2].u4 = Bs[(r << 3) + (kb ^ (r & 7))];
      }
      #pragma unroll
      for (int m2 = 0; m2 < 2; m2++)
        #pragma unroll
        for (int n2 = 0; n2 < 2; n2++)
          acc[m2][n2] = __builtin_amdgcn_mfma_f32_16x16x32_bf16(
              a[m2].s8, b[n2].s8, acc[m2][n2], 0, 0, 0);
    }
    __syncthreads();
  }
  #pragma unroll
  for (int m2 = 0; m2 < 2; m2++)
    #pragma unroll
    for (int n2 = 0; n2 < 2; n2++)
      #pragma unroll
      for (int q = 0; q < 4; q++) {
        size_t gr = row0 + (wm << 5) + (m2 << 4) + (kg << 2) + q;
        int gc = col0 + (wn << 5) + (n2 << 4) + r16;
        h_bf[gr * D_ + gc] = f2bf(acc[m2][n2][q] + bias[gc]);
      }
}

// ---------------- s/t: per-row dots with a_self / a_neigh (bf16 h) ----------
__global__ __launch_bounds__(256) void st_kernel(const u16* __restrict__ h_bf,
    const float* __restrict__ a_self, const float* __restrict__ a_nei,
    float* __restrict__ s, float* __restrict__ t) {
  int wave = threadIdx.x >> 6, lane = threadIdx.x & 63;
  int row = (blockIdx.x << 2) + wave;
  U16x8 hv; hv.u4 = *(const uint4*)(h_bf + ((size_t)row << 8) + (lane << 3));
  float4 a0 = *(const float4*)(a_self + lane * 8);
  float4 a1 = *(const float4*)(a_self + lane * 8 + 4);
  float4 b0 = *(const float4*)(a_nei + lane * 8);
  float4 b1 = *(const float4*)(a_nei + lane * 8 + 4);
  float av[8] = {a0.x, a0.y, a0.z, a0.w, a1.x, a1.y, a1.z, a1.w};
  float bv[8] = {b0.x, b0.y, b0.z, b0.w, b1.x, b1.y, b1.z, b1.w};
  float ds = 0.f, dn = 0.f;
  #pragma unroll
  for (int q = 0; q < 8; q++) {
    float hf = bf2f((u16)hv.s8[q]);
    ds = __builtin_fmaf(hf, av[q], ds);
    dn = __builtin_fmaf(hf, bv[q], dn);
  }
  #pragma unroll
  for (int off = 32; off; off >>= 1) { ds += __shfl_down(ds, off); dn += __shfl_down(dn, off); }
  if (lane == 0) { s[row] = ds; t[row] = dn; }
}

// -------- fused masked-softmax + wave-parallel bf16 gather-SpMM + tanh(elu) --
#define MAXN 512
__global__ __launch_bounds__(256) void attn2_kernel(const int* __restrict__ adj,
    const u16* __restrict__ h_bf, const float* __restrict__ s,
    const float* __restrict__ t, u16* __restrict__ g_bf) {
  __shared__ int nidx[MAXN];
  __shared__ float ne[MAXN];
  __shared__ float red[4][256];
  __shared__ int wtot[4];
  __shared__ float redm[4];
  __shared__ float reds[4];
  const int tid = threadIdx.x;
  const int row = blockIdx.x;
  const int lane = tid & 63, wave = tid >> 6;
  const int4* arow = (const int4*)(adj + (size_t)row * NN_);
  int4 a4[4];
  #pragma unroll
  for (int i = 0; i < 4; i++) a4[i] = arow[(i << 8) + tid];
  int vals[16] = {a4[0].x, a4[0].y, a4[0].z, a4[0].w, a4[1].x, a4[1].y, a4[1].z, a4[1].w,
                  a4[2].x, a4[2].y, a4[2].z, a4[2].w, a4[3].x, a4[3].y, a4[3].z, a4[3].w};
  int c = 0;
  #pragma unroll
  for (int q = 0; q < 16; q++) c += (vals[q] > 0);
  int pref = c;
  #pragma unroll
  for (int off = 1; off < 64; off <<= 1) {
    int u = __shfl_up(pref, off);
    if (lane >= off) pref += u;
  }
  if (lane == 63) wtot[wave] = pref;
  __syncthreads();                                       // B1
  int woff = 0;
  #pragma unroll
  for (int w = 0; w < 4; w++) woff += (w < wave) ? wtot[w] : 0;
  int n = wtot[0] + wtot[1] + wtot[2] + wtot[3];
  float si = s[row];
  int p = woff + pref - c;
  #pragma unroll
  for (int i = 0; i < 4; i++)
    #pragma unroll
    for (int q = 0; q < 4; q++) {
      if (vals[(i << 2) + q] > 0) {
        int j = (i << 10) + (tid << 2) + q;
        float e = 0.2f * (si + t[j]);
        e = e > 0.f ? e : 0.2f * e;
        if (p < MAXN) { nidx[p] = j; ne[p] = e; }
        p++;
      }
    }
  if (n > MAXN) n = MAXN;
  __syncthreads();                                       // B2
  float lm = -3.0e38f;
  if (tid < n) lm = ne[tid];
  if (tid + 256 < n) lm = fmaxf(lm, ne[tid + 256]);
  #pragma unroll
  for (int off = 32; off; off >>= 1) lm = fmaxf(lm, __shfl_xor(lm, off));
  if (lane == 0) redm[wave] = lm;
  __syncthreads();                                       // B3
  float m = fmaxf(fmaxf(redm[0], redm[1]), fmaxf(redm[2], redm[3]));
  float ls = 0.f;
  if (tid < n)       { float w0 = __expf(ne[tid] - m);       ne[tid] = w0;       ls += w0; }
  if (tid + 256 < n) { float w1 = __expf(ne[tid + 256] - m); ne[tid + 256] = w1; ls += w1; }
  #pragma unroll
  for (int off = 32; off; off >>= 1) ls += __shfl_xor(ls, off);
  if (lane == 0) reds[wave] = ls;
  __syncthreads();                                       // B4
  float S = reds[0] + reds[1] + reds[2] + reds[3];
  const int hl = lane & 31, ksel = lane >> 5;
  float acc[8] = {0.f, 0.f, 0.f, 0.f, 0.f, 0.f, 0.f, 0.f};
  for (int k = (wave << 1) + ksel; k < n; k += 8) {
    float wgt = ne[k];
    int j = nidx[k];
    U16x8 hv; hv.u4 = *(const uint4*)(h_bf + ((size_t)j << 8) + (hl << 3));
    #pragma unroll
    for (int q = 0; q < 8; q++)
      acc[q] = __builtin_fmaf(wgt, bf2f((u16)hv.s8[q]), acc[q]);
  }
  #pragma unroll
  for (int q = 0; q < 8; q++) acc[q] += __shfl_down(acc[q], 32);
  if (lane < 32) {
    #pragma unroll
    for (int q = 0; q < 8; q++) red[wave][(hl << 3) + q] = acc[q];
  }
  __syncthreads();                                       // B5
  float hp;
  if (n > 0) {
    hp = (red[0][tid] + red[1][tid] + red[2][tid] + red[3][tid]) / S;
  } else {
    float a2 = 0.f;
    for (int j = 0; j < NN_; j++) a2 += bf2f(h_bf[((size_t)j << 8) + tid]);
    hp = a2 / NN_;
  }
  float el = hp > 0.f ? hp : __expf(hp) - 1.f;
  g_bf[((size_t)row << 8) + tid] = f2bf(tanhf(el));
}

// ------- gates GEMM (permuted Wih) + fused LSTM cell -> h1 bf16. grid (8,32) -
__global__ __launch_bounds__(256) void gates_lstm_kernel(const u16* __restrict__ A,
    const u16* __restrict__ B, u16* __restrict__ h1b) {
  __shared__ uint4 As[128 * 8];
  __shared__ uint4 Bs[128 * 8];
  const int tid = threadIdx.x;
  const int row0 = blockIdx.y << 7, col0 = blockIdx.x << 7;
  f32x4 acc[4][4];
  #pragma unroll
  for (int m2 = 0; m2 < 4; m2++)
    #pragma unroll
    for (int n2 = 0; n2 < 4; n2++) acc[m2][n2] = (f32x4){0.f,0.f,0.f,0.f};
  mfma_mainloop(A, B, D_, D_, D_, row0, col0, As, Bs, acc, tid);
  const int wave = tid >> 6, lane = tid & 63;
  const int r16 = lane & 15, kg = lane >> 4;
  const int orow = row0 + ((wave >> 1) << 6);
  const int hc = ((blockIdx.x << 1) + (wave & 1)) * 16 + r16;
  #pragma unroll
  for (int m2 = 0; m2 < 4; m2++)
    #pragma unroll
    for (int q = 0; q < 4; q++) {
      size_t grow = orow + (m2 << 4) + (kg << 2) + q;
      float ig = acc[m2][0][q], gg = acc[m2][2][q], og = acc[m2][3][q];
      float c1 = sigm(ig) * tanhf(gg);
      h1b[grow * D_ + hc] = f2bf(sigm(og) * tanhf(c1));
    }
}

// ------- fused lin2 + bias + L2-normalize. 64x128 tile, grid 64 --------------
__global__ __launch_bounds__(256) void lin2f_kernel(const u16* __restrict__ A,
    const u16* __restrict__ B, const float* __restrict__ bias,
    float* __restrict__ out, float* __restrict__ z, u16* __restrict__ zb) {
  __shared__ uint4 As[64 * 8];
  __shared__ uint4 Bs[128 * 8];
  const int tid = threadIdx.x;
  const int wave = tid >> 6, lane = tid & 63;
  const int r16 = lane & 15, kg = lane >> 4;
  const int row0 = blockIdx.x << 6;
  f32x4 acc[8];
  #pragma unroll
  for (int n2 = 0; n2 < 8; n2++) acc[n2] = (f32x4){0.f,0.f,0.f,0.f};
  for (int k0 = 0; k0 < 256; k0 += 64) {
    #pragma unroll
    for (int i = 0; i < 2; i++) {
      int id = tid + (i << 8);
      int r = id >> 3, cc = id & 7;
      As[(r << 3) + (cc ^ (r & 7))] = *(const uint4*)(A + (size_t)(row0 + r) * 256 + k0 + cc * 8);
    }
    #pragma unroll
    for (int i = 0; i < 4; i++) {
      int id = tid + (i << 8);
      int r = id >> 3, cc = id & 7;
      Bs[(r << 3) + (cc ^ (r & 7))] = *(const uint4*)(B + (size_t)r * 256 + k0 + cc * 8);
    }
    __syncthreads();
    #pragma unroll
    for (int ks = 0; ks < 2; ks++) {
      int kb = (ks << 2) + kg;
      U16x8 a, b[8];
      int ra = (wave << 4) + r16;
      a.u4 = As[(ra << 3) + (kb ^ (ra & 7))];
      #pragma unroll
      for (int n2 = 0; n2 < 8; n2++) {
        int r = (n2 << 4) + r16;
        b[n2].u4 = Bs[(r << 3) + (kb ^ (r & 7))];
      }
      #pragma unroll
      for (int n2 = 0; n2 < 8; n2++)
        acc[n2] = __builtin_amdgcn_mfma_f32_16x16x32_bf16(a.s8, b[n2].s8, acc[n2], 0, 0, 0);
    }
    __syncthreads();
  }
  #pragma unroll
  for (int q = 0; q < 4; q++) {
    size_t grow = row0 + (wave << 4) + (kg << 2) + q;
    float v[8]; float ss = 0.f;
    #pragma unroll
    for (int n2 = 0; n2 < 8; n2++) {
      float vv = acc[n2][q] + bias[(n2 << 4) + r16];
      v[n2] = vv; ss = __builtin_fmaf(vv, vv, ss);
    }
    ss += __shfl_xor(ss, 1); ss += __shfl_xor(ss, 2);
    ss += __shfl_xor(ss, 4); ss += __shfl_xor(ss, 8);
    float inv = 1.f / fmaxf(sqrtf(ss), 1e-12f);
    #pragma unroll
    for (int n2 = 0; n2 < 8; n2++) {
      int gc = (n2 << 4) + r16;
      float vv = v[n2], zz = vv * inv;
      out[grow * OUT_ + gc] = vv;
      z[grow * OUT_ + gc] = zz;
      zb[grow * OUT_ + gc] = f2bf(zz);
    }
  }
}

// ------- decode: A_pred = sigmoid(z z^T), full grid 1024, coalesced ----------
__global__ __launch_bounds__(256) void decode_kernel(const u16* __restrict__ zb,
    float* __restrict__ C) {
  __shared__ uint4 As[128 * 8];
  __shared__ uint4 Bs[128 * 8];
  const int tid = threadIdx.x;
  const int row0 = blockIdx.y << 7, col0 = blockIdx.x << 7;
  f32x4 acc[4][4];
  #pragma unroll
  for (int m2 = 0; m2 < 4; m2++)
    #pragma unroll
    for (int n2 = 0; n2 < 4; n2++) acc[m2][n2] = (f32x4){0.f,0.f,0.f,0.f};
  mfma_mainloop(zb, zb, OUT_, OUT_, OUT_, row0, col0, As, Bs, acc, tid);
  const int wave = tid >> 6, lane = tid & 63;
  const int r16 = lane & 15, kg = lane >> 4;
  const int orow = row0 + ((wave >> 1) << 6), ocol = col0 + ((wave & 1) << 6);
  #pragma unroll
  for (int m2 = 0; m2 < 4; m2++)
    #pragma unroll
    for (int n2 = 0; n2 < 4; n2++)
      #pragma unroll
      for (int q = 0; q < 4; q++) {
        size_t gr = orow + (m2 << 4) + (kg << 2) + q;
        int gc = ocol + (n2 << 4) + r16;
        C[gr * NN_ + gc] = sigm(acc[m2][n2][q]);
      }
}

extern "C" void kernel_launch(void* const* d_in, const int* in_sizes, int n_in,
                              void* d_out, int out_size, void* d_ws, size_t ws_size,
                              hipStream_t stream) {
  const float* x      = (const float*)d_in[0];
  const int*   adj    = (const int*)  d_in[1];
  const float* lin1_w = (const float*)d_in[2];
  const float* lin1_b = (const float*)d_in[3];
  const float* gat_W  = (const float*)d_in[4];
  const float* a_self = (const float*)d_in[5];
  const float* a_nei  = (const float*)d_in[6];
  const float* W_ih   = (const float*)d_in[7];
  const float* lin2_w = (const float*)d_in[9];
  const float* lin2_b = (const float*)d_in[10];

  float* A_pred = (float*)d_out;
  float* z_out  = A_pred + (size_t)NN_ * NN_;
  float* out_o  = z_out + (size_t)NN_ * OUT_;

  char* w = (char*)d_ws;
  u16* h_bf   = (u16*)w;                                 // 2 MB
  u16* g_bf   = (u16*)(w + (2u << 20));                  // 2 MB
  u16* h1_bf  = (u16*)(w + (4u << 20));                  // 2 MB
  u16* zb     = (u16*)(w + (6u << 20));                  // 1 MB
  u16* Wih_bf = (u16*)(w + (7u << 20));                  // 512 KB
  u16* WcT_bf = (u16*)(w + (7u << 20) + (512u << 10));   // 256 KB
  u16* l2w_bf = (u16*)(w + (7u << 20) + (768u << 10));   // 64 KB
  float* bcomb= (float*)(w + (7u << 20) + (832u << 10)); // 1 KB
  float* s    = (float*)(w + (7u << 20) + (896u << 10)); // 16 KB
  float* t    = (float*)(w + (7u << 20) + (960u << 10)); // 16 KB

  prep_kernel<<<dim3(321), dim3(256), 0, stream>>>(
      W_ih, lin2_w, lin1_w, gat_W, lin1_b, Wih_bf, l2w_bf, WcT_bf, bcomb);
  hgemm_kernel<<<dim3(4, 64), dim3(256), 0, stream>>>(x, WcT_bf, bcomb, h_bf);
  st_kernel<<<dim3(1024), dim3(256), 0, stream>>>(h_bf, a_self, a_nei, s, t);
  attn2_kernel<<<dim3(4096), dim3(256), 0, stream>>>(adj, h_bf, s, t, g_bf);
  gates_lstm_kernel<<<dim3(8, 32), dim3(256), 0, stream>>>(g_bf, Wih_bf, h1_bf);
  lin2f_kernel<<<dim3(64), dim3(256), 0, stream>>>(h1_bf, l2w_bf, lin2_b, out_o, z_out, zb);
  decode_kernel<<<dim3(32, 32), dim3(256), 0, stream>>>(zb, A_pred);
}

// Round 8
// 88.057 us; speedup vs baseline: 7.8147x; 1.1789x over previous
//
#include <hip/hip_runtime.h>

#define NN_ 4096
#define IN_DIM_ 512
#define D_ 256
#define OUT_ 128

typedef unsigned short u16;
typedef unsigned int u32;
typedef __attribute__((ext_vector_type(8))) short short8;
typedef __attribute__((ext_vector_type(4))) float f32x4;

union U16x8 { uint4 u4; short8 s8; };

__device__ __forceinline__ u16 f2bf(float f){
  u32 u = __builtin_bit_cast(u32, f);
  u = (u + 0x7FFFu + ((u >> 16) & 1u)) >> 16;
  return (u16)u;
}
__device__ __forceinline__ float bf2f(u16 u){ return __builtin_bit_cast(float, ((u32)u) << 16); }
__device__ __forceinline__ float sigm(float v){ return __fdividef(1.f, 1.f + __expf(-v)); }

// ---------- MFMA mainloop: 128x128 tile, BK=64, 4 waves (2x2), XOR-swizzle --
__device__ __forceinline__ void mfma_mainloop(const u16* __restrict__ A,
    const u16* __restrict__ B, int K, int ldA, int ldB, int row0, int col0,
    uint4* As, uint4* Bs, f32x4 acc[4][4], int tid) {
  const int wave = tid >> 6, lane = tid & 63;
  const int wm = wave >> 1, wn = wave & 1;
  const int r16 = lane & 15, kg = lane >> 4;
  for (int k0 = 0; k0 < K; k0 += 64) {
    #pragma unroll
    for (int i = 0; i < 4; i++) {
      int id = tid + (i << 8);
      int r = id >> 3, cc = id & 7;
      As[(r << 3) + (cc ^ (r & 7))] = *(const uint4*)(A + (size_t)(row0 + r) * ldA + k0 + cc * 8);
      Bs[(r << 3) + (cc ^ (r & 7))] = *(const uint4*)(B + (size_t)(col0 + r) * ldB + k0 + cc * 8);
    }
    __syncthreads();
    #pragma unroll
    for (int ks = 0; ks < 2; ks++) {
      int kb = (ks << 2) + kg;
      U16x8 a[4], b[4];
      #pragma unroll
      for (int m2 = 0; m2 < 4; m2++) {
        int r = (wm << 6) + (m2 << 4) + r16;
        a[m2].u4 = As[(r << 3) + (kb ^ (r & 7))];
      }
      #pragma unroll
      for (int n2 = 0; n2 < 4; n2++) {
        int r = (wn << 6) + (n2 << 4) + r16;
        b[n2].u4 = Bs[(r << 3) + (kb ^ (r & 7))];
      }
      #pragma unroll
      for (int m2 = 0; m2 < 4; m2++)
        #pragma unroll
        for (int n2 = 0; n2 < 4; n2++)
          acc[m2][n2] = __builtin_amdgcn_mfma_f32_16x16x32_bf16(
              a[m2].s8, b[n2].s8, acc[m2][n2], 0, 0, 0);
    }
    __syncthreads();
  }
}

// ------------- prep: Wcomb (32 tiles) + bcomb (1) ---------------------------
__global__ __launch_bounds__(256) void prep_kernel(
    const float* __restrict__ lin1_w, const float* __restrict__ gat_W,
    const float* __restrict__ lin1_b,
    u16* __restrict__ WcT_bf, float* __restrict__ bcomb) {
  __shared__ __align__(16) float sh[2 * 32 * 68];
  const int b = blockIdx.x, tid = threadIdx.x;
  if (b < 32) {
    // Wcomb[m][n] = sum_k lin1_w[k][m]*gat_W[k][n]; store transposed bf16
    float (*As)[68] = (float(*)[68])sh;
    float (*Bs)[68] = (float(*)[68])(sh + 32 * 68);
    int m0 = (b & 7) << 6, n0 = (b >> 3) << 6;
    const int tx = tid & 15, ty = tid >> 4;
    float acc[4][4] = {};
    for (int k0 = 0; k0 < 256; k0 += 32) {
      #pragma unroll
      for (int i = 0; i < 2; i++) {
        int id = tid + (i << 8);
        int kk = id >> 4, c4 = (id & 15) << 2;
        *(float4*)&As[kk][c4] = *(const float4*)(lin1_w + (size_t)(k0 + kk) * 512 + m0 + c4);
        *(float4*)&Bs[kk][c4] = *(const float4*)(gat_W + (size_t)(k0 + kk) * 256 + n0 + c4);
      }
      __syncthreads();
      #pragma unroll
      for (int kk = 0; kk < 32; kk++) {
        float4 av = *(const float4*)&As[kk][ty << 2];
        float4 bv = *(const float4*)&Bs[kk][tx << 2];
        float a_[4] = {av.x, av.y, av.z, av.w};
        float b_[4] = {bv.x, bv.y, bv.z, bv.w};
        #pragma unroll
        for (int r = 0; r < 4; r++)
          #pragma unroll
          for (int c = 0; c < 4; c++)
            acc[r][c] = __builtin_fmaf(a_[r], b_[c], acc[r][c]);
      }
      __syncthreads();
    }
    #pragma unroll
    for (int r = 0; r < 4; r++)
      #pragma unroll
      for (int c = 0; c < 4; c++)
        WcT_bf[(size_t)(n0 + (tx << 2) + c) * 512 + m0 + (ty << 2) + r] = f2bf(acc[r][c]);
  } else {
    float a = 0.f;
    #pragma unroll 8
    for (int d = 0; d < 256; d++)
      a = __builtin_fmaf(lin1_b[d], gat_W[(size_t)d * 256 + tid], a);
    bcomb[tid] = a;
  }
}

// ---- h = x @ Wcomb + bcomb -> bf16, fused s/t row dots. 16x256 tiles -------
// blocks [0,256): gemm+st | [256,512): Wih permute convert | [512,544): l2w
__global__ __launch_bounds__(256) void hgemm_st_kernel(const float* __restrict__ x,
    const u16* __restrict__ WcT, const float* __restrict__ bias,
    const float* __restrict__ a_self, const float* __restrict__ a_nei,
    const float* __restrict__ W_ih, const float* __restrict__ lin2_w,
    u16* __restrict__ h_bf, float* __restrict__ s, float* __restrict__ t,
    u16* __restrict__ Wih_bf, u16* __restrict__ l2w_bf) {
  __shared__ uint4 As[16 * 8];
  __shared__ uint4 Bs[256 * 8];
  __shared__ float sred[4][16];
  __shared__ float tred[4][16];
  const int tid = threadIdx.x;
  int b = blockIdx.x;
  if (b >= 256) {
    b -= 256;
    if (b < 256) {
      // permuted Wih: new row r -> orig = gate*256 + grp*16 + hcl
      int r = (b << 2) + (tid >> 6);
      int grp = r >> 6, gate = (r >> 4) & 3, hcl = r & 15;
      int orig = gate * 256 + grp * 16 + hcl;
      int k = (tid & 63) << 2;
      float4 v = *(const float4*)(W_ih + (size_t)orig * 256 + k);
      ushort4 o = {f2bf(v.x), f2bf(v.y), f2bf(v.z), f2bf(v.w)};
      *(ushort4*)(Wih_bf + (size_t)r * 256 + k) = o;
    } else {
      int off = (b - 256) * 1024 + tid * 4;
      float4 v = *(const float4*)(lin2_w + off);
      ushort4 o = {f2bf(v.x), f2bf(v.y), f2bf(v.z), f2bf(v.w)};
      *(ushort4*)(l2w_bf + off) = o;
    }
    return;
  }
  const int row0 = b << 4;
  const int wave = tid >> 6, lane = tid & 63;
  const int r16 = lane & 15, kg = lane >> 4;
  f32x4 acc[4];
  #pragma unroll
  for (int n2 = 0; n2 < 4; n2++) acc[n2] = (f32x4){0.f,0.f,0.f,0.f};
  for (int k0 = 0; k0 < IN_DIM_; k0 += 64) {
    if (tid < 128) {          // A: 16 rows x 64 k, fp32 -> bf16 in staging
      int r = tid >> 3, cc = tid & 7;
      const float* src = x + (size_t)(row0 + r) * IN_DIM_ + k0 + cc * 8;
      float4 lo = *(const float4*)src;
      float4 hi = *(const float4*)(src + 4);
      u16 e[8] = {f2bf(lo.x), f2bf(lo.y), f2bf(lo.z), f2bf(lo.w),
                  f2bf(hi.x), f2bf(hi.y), f2bf(hi.z), f2bf(hi.w)};
      As[(r << 3) + (cc ^ (r & 7))] = *(uint4*)e;
    }
    #pragma unroll
    for (int i = 0; i < 8; i++) {   // B: all 256 WcT rows x 64 k
      int id = tid + (i << 8);
      int r = id >> 3, cc = id & 7;
      Bs[(r << 3) + (cc ^ (r & 7))] = *(const uint4*)(WcT + (size_t)r * IN_DIM_ + k0 + cc * 8);
    }
    __syncthreads();
    #pragma unroll
    for (int ks = 0; ks < 2; ks++) {
      int kb = (ks << 2) + kg;
      U16x8 a, bb[4];
      a.u4 = As[(r16 << 3) + (kb ^ (r16 & 7))];
      #pragma unroll
      for (int n2 = 0; n2 < 4; n2++) {
        int r = (wave << 6) + (n2 << 4) + r16;
        bb[n2].u4 = Bs[(r << 3) + (kb ^ (r & 7))];
      }
      #pragma unroll
      for (int n2 = 0; n2 < 4; n2++)
        acc[n2] = __builtin_amdgcn_mfma_f32_16x16x32_bf16(a.s8, bb[n2].s8, acc[n2], 0, 0, 0);
    }
    __syncthreads();
  }
  // epilogue: bias, bf16 store, per-row s/t partials
  float ps[4] = {0.f,0.f,0.f,0.f}, pt[4] = {0.f,0.f,0.f,0.f};
  #pragma unroll
  for (int n2 = 0; n2 < 4; n2++) {
    int col = (wave << 6) + (n2 << 4) + r16;
    float as = a_self[col], an = a_nei[col], bs = bias[col];
    #pragma unroll
    for (int q = 0; q < 4; q++) {
      float v = acc[n2][q] + bs;
      h_bf[(size_t)(row0 + (kg << 2) + q) * D_ + col] = f2bf(v);
      ps[q] = __builtin_fmaf(v, as, ps[q]);
      pt[q] = __builtin_fmaf(v, an, pt[q]);
    }
  }
  #pragma unroll
  for (int q = 0; q < 4; q++) {
    #pragma unroll
    for (int off = 8; off; off >>= 1) {
      ps[q] += __shfl_xor(ps[q], off);
      pt[q] += __shfl_xor(pt[q], off);
    }
  }
  if (r16 == 0) {
    #pragma unroll
    for (int q = 0; q < 4; q++) {
      sred[wave][(kg << 2) + q] = ps[q];
      tred[wave][(kg << 2) + q] = pt[q];
    }
  }
  __syncthreads();
  if (tid < 16)
    s[row0 + tid] = sred[0][tid] + sred[1][tid] + sred[2][tid] + sred[3][tid];
  else if (tid < 32)
    t[row0 + tid - 16] = tred[0][tid-16] + tred[1][tid-16] + tred[2][tid-16] + tred[3][tid-16];
}

// -------- fused masked-softmax + wave-parallel bf16 gather-SpMM + tanh(elu) --
#define MAXN 512
__global__ __launch_bounds__(256) void attn2_kernel(const int* __restrict__ adj,
    const u16* __restrict__ h_bf, const float* __restrict__ s,
    const float* __restrict__ t, u16* __restrict__ g_bf) {
  __shared__ int nidx[MAXN];
  __shared__ float ne[MAXN];
  __shared__ float red[4][256];
  __shared__ int wtot[4];
  __shared__ float redm[4];
  __shared__ float reds[4];
  const int tid = threadIdx.x;
  const int row = blockIdx.x;
  const int lane = tid & 63, wave = tid >> 6;
  const int4* arow = (const int4*)(adj + (size_t)row * NN_);
  int4 a4[4];
  #pragma unroll
  for (int i = 0; i < 4; i++) a4[i] = arow[(i << 8) + tid];
  int vals[16] = {a4[0].x, a4[0].y, a4[0].z, a4[0].w, a4[1].x, a4[1].y, a4[1].z, a4[1].w,
                  a4[2].x, a4[2].y, a4[2].z, a4[2].w, a4[3].x, a4[3].y, a4[3].z, a4[3].w};
  int c = 0;
  #pragma unroll
  for (int q = 0; q < 16; q++) c += (vals[q] > 0);
  int pref = c;
  #pragma unroll
  for (int off = 1; off < 64; off <<= 1) {
    int u = __shfl_up(pref, off);
    if (lane >= off) pref += u;
  }
  if (lane == 63) wtot[wave] = pref;
  __syncthreads();                                       // B1
  int woff = 0;
  #pragma unroll
  for (int w = 0; w < 4; w++) woff += (w < wave) ? wtot[w] : 0;
  int n = wtot[0] + wtot[1] + wtot[2] + wtot[3];
  float si = s[row];
  int p = woff + pref - c;
  #pragma unroll
  for (int i = 0; i < 4; i++)
    #pragma unroll
    for (int q = 0; q < 4; q++) {
      if (vals[(i << 2) + q] > 0) {
        int j = (i << 10) + (tid << 2) + q;
        float e = 0.2f * (si + t[j]);
        e = e > 0.f ? e : 0.2f * e;
        if (p < MAXN) { nidx[p] = j; ne[p] = e; }
        p++;
      }
    }
  if (n > MAXN) n = MAXN;
  __syncthreads();                                       // B2
  float lm = -3.0e38f;
  if (tid < n) lm = ne[tid];
  if (tid + 256 < n) lm = fmaxf(lm, ne[tid + 256]);
  #pragma unroll
  for (int off = 32; off; off >>= 1) lm = fmaxf(lm, __shfl_xor(lm, off));
  if (lane == 0) redm[wave] = lm;
  __syncthreads();                                       // B3
  float m = fmaxf(fmaxf(redm[0], redm[1]), fmaxf(redm[2], redm[3]));
  float ls = 0.f;
  if (tid < n)       { float w0 = __expf(ne[tid] - m);       ne[tid] = w0;       ls += w0; }
  if (tid + 256 < n) { float w1 = __expf(ne[tid + 256] - m); ne[tid + 256] = w1; ls += w1; }
  #pragma unroll
  for (int off = 32; off; off >>= 1) ls += __shfl_xor(ls, off);
  if (lane == 0) reds[wave] = ls;
  __syncthreads();                                       // B4
  float S = reds[0] + reds[1] + reds[2] + reds[3];
  const int hl = lane & 31, ksel = lane >> 5;
  float acc[8] = {0.f, 0.f, 0.f, 0.f, 0.f, 0.f, 0.f, 0.f};
  #pragma unroll 4
  for (int k = (wave << 1) + ksel; k < n; k += 8) {
    float wgt = ne[k];
    int j = nidx[k];
    U16x8 hv; hv.u4 = *(const uint4*)(h_bf + ((size_t)j << 8) + (hl << 3));
    #pragma unroll
    for (int q = 0; q < 8; q++)
      acc[q] = __builtin_fmaf(wgt, bf2f((u16)hv.s8[q]), acc[q]);
  }
  #pragma unroll
  for (int q = 0; q < 8; q++) acc[q] += __shfl_down(acc[q], 32);
  if (lane < 32) {
    #pragma unroll
    for (int q = 0; q < 8; q++) red[wave][(hl << 3) + q] = acc[q];
  }
  __syncthreads();                                       // B5
  float hp;
  if (n > 0) {
    hp = (red[0][tid] + red[1][tid] + red[2][tid] + red[3][tid]) / S;
  } else {
    float a2 = 0.f;
    for (int j = 0; j < NN_; j++) a2 += bf2f(h_bf[((size_t)j << 8) + tid]);
    hp = a2 / NN_;
  }
  float el = hp > 0.f ? hp : __expf(hp) - 1.f;
  g_bf[((size_t)row << 8) + tid] = f2bf(tanhf(el));
}

// ------- gates GEMM (permuted Wih) + fused LSTM cell -> h1 bf16. grid (8,32) -
__global__ __launch_bounds__(256) void gates_lstm_kernel(const u16* __restrict__ A,
    const u16* __restrict__ B, u16* __restrict__ h1b) {
  __shared__ uint4 As[128 * 8];
  __shared__ uint4 Bs[128 * 8];
  const int tid = threadIdx.x;
  const int row0 = blockIdx.y << 7, col0 = blockIdx.x << 7;
  f32x4 acc[4][4];
  #pragma unroll
  for (int m2 = 0; m2 < 4; m2++)
    #pragma unroll
    for (int n2 = 0; n2 < 4; n2++) acc[m2][n2] = (f32x4){0.f,0.f,0.f,0.f};
  mfma_mainloop(A, B, D_, D_, D_, row0, col0, As, Bs, acc, tid);
  const int wave = tid >> 6, lane = tid & 63;
  const int r16 = lane & 15, kg = lane >> 4;
  const int orow = row0 + ((wave >> 1) << 6);
  const int hc = ((blockIdx.x << 1) + (wave & 1)) * 16 + r16;
  #pragma unroll
  for (int m2 = 0; m2 < 4; m2++)
    #pragma unroll
    for (int q = 0; q < 4; q++) {
      size_t grow = orow + (m2 << 4) + (kg << 2) + q;
      float ig = acc[m2][0][q], gg = acc[m2][2][q], og = acc[m2][3][q];
      float c1 = sigm(ig) * tanhf(gg);
      h1b[grow * D_ + hc] = f2bf(sigm(og) * tanhf(c1));
    }
}

// ------- fused lin2 + bias + L2-normalize. 16x128 tiles, grid 256 ------------
__global__ __launch_bounds__(256) void lin2f_kernel(const u16* __restrict__ A,
    const u16* __restrict__ B, const float* __restrict__ bias,
    float* __restrict__ out, float* __restrict__ z, u16* __restrict__ zb) {
  __shared__ uint4 As[16 * 8];
  __shared__ uint4 Bs[128 * 8];
  __shared__ float ssred[4][16];
  const int tid = threadIdx.x;
  const int wave = tid >> 6, lane = tid & 63;
  const int r16 = lane & 15, kg = lane >> 4;
  const int row0 = blockIdx.x << 4;
  f32x4 acc[2];
  acc[0] = (f32x4){0.f,0.f,0.f,0.f}; acc[1] = (f32x4){0.f,0.f,0.f,0.f};
  for (int k0 = 0; k0 < D_; k0 += 64) {
    if (tid < 128) {
      int r = tid >> 3, cc = tid & 7;
      As[(r << 3) + (cc ^ (r & 7))] = *(const uint4*)(A + (size_t)(row0 + r) * D_ + k0 + cc * 8);
    }
    #pragma unroll
    for (int i = 0; i < 4; i++) {
      int id = tid + (i << 8);
      int r = id >> 3, cc = id & 7;
      Bs[(r << 3) + (cc ^ (r & 7))] = *(const uint4*)(B + (size_t)r * D_ + k0 + cc * 8);
    }
    __syncthreads();
    #pragma unroll
    for (int ks = 0; ks < 2; ks++) {
      int kb = (ks << 2) + kg;
      U16x8 a, bb[2];
      a.u4 = As[(r16 << 3) + (kb ^ (r16 & 7))];
      #pragma unroll
      for (int n2 = 0; n2 < 2; n2++) {
        int r = (wave << 5) + (n2 << 4) + r16;
        bb[n2].u4 = Bs[(r << 3) + (kb ^ (r & 7))];
      }
      #pragma unroll
      for (int n2 = 0; n2 < 2; n2++)
        acc[n2] = __builtin_amdgcn_mfma_f32_16x16x32_bf16(a.s8, bb[n2].s8, acc[n2], 0, 0, 0);
    }
    __syncthreads();
  }
  float v[2][4], ss[4];
  #pragma unroll
  for (int q = 0; q < 4; q++) ss[q] = 0.f;
  #pragma unroll
  for (int n2 = 0; n2 < 2; n2++) {
    int col = (wave << 5) + (n2 << 4) + r16;
    float bs = bias[col];
    #pragma unroll
    for (int q = 0; q < 4; q++) {
      float vv = acc[n2][q] + bs;
      v[n2][q] = vv;
      ss[q] = __builtin_fmaf(vv, vv, ss[q]);
    }
  }
  #pragma unroll
  for (int q = 0; q < 4; q++)
    #pragma unroll
    for (int off = 8; off; off >>= 1) ss[q] += __shfl_xor(ss[q], off);
  if (r16 == 0) {
    #pragma unroll
    for (int q = 0; q < 4; q++) ssred[wave][(kg << 2) + q] = ss[q];
  }
  __syncthreads();
  #pragma unroll
  for (int q = 0; q < 4; q++) {
    int rrow = (kg << 2) + q;
    float tot = ssred[0][rrow] + ssred[1][rrow] + ssred[2][rrow] + ssred[3][rrow];
    float inv = __fdividef(1.f, fmaxf(sqrtf(tot), 1e-12f));
    size_t grow = row0 + rrow;
    #pragma unroll
    for (int n2 = 0; n2 < 2; n2++) {
      int col = (wave << 5) + (n2 << 4) + r16;
      float vv = v[n2][q], zz = vv * inv;
      out[grow * OUT_ + col] = vv;
      z[grow * OUT_ + col] = zz;
      zb[grow * OUT_ + col] = f2bf(zz);
    }
  }
}

// ------- decode: A_pred = sigmoid(z z^T), full grid 1024, coalesced ----------
__global__ __launch_bounds__(256) void decode_kernel(const u16* __restrict__ zb,
    float* __restrict__ C) {
  __shared__ uint4 As[128 * 8];
  __shared__ uint4 Bs[128 * 8];
  const int tid = threadIdx.x;
  const int row0 = blockIdx.y << 7, col0 = blockIdx.x << 7;
  f32x4 acc[4][4];
  #pragma unroll
  for (int m2 = 0; m2 < 4; m2++)
    #pragma unroll
    for (int n2 = 0; n2 < 4; n2++) acc[m2][n2] = (f32x4){0.f,0.f,0.f,0.f};
  mfma_mainloop(zb, zb, OUT_, OUT_, OUT_, row0, col0, As, Bs, acc, tid);
  const int wave = tid >> 6, lane = tid & 63;
  const int r16 = lane & 15, kg = lane >> 4;
  const int orow = row0 + ((wave >> 1) << 6), ocol = col0 + ((wave & 1) << 6);
  #pragma unroll
  for (int m2 = 0; m2 < 4; m2++)
    #pragma unroll
    for (int n2 = 0; n2 < 4; n2++)
      #pragma unroll
      for (int q = 0; q < 4; q++) {
        size_t gr = orow + (m2 << 4) + (kg << 2) + q;
        int gc = ocol + (n2 << 4) + r16;
        C[gr * NN_ + gc] = sigm(acc[m2][n2][q]);
      }
}

extern "C" void kernel_launch(void* const* d_in, const int* in_sizes, int n_in,
                              void* d_out, int out_size, void* d_ws, size_t ws_size,
                              hipStream_t stream) {
  const float* x      = (const float*)d_in[0];
  const int*   adj    = (const int*)  d_in[1];
  const float* lin1_w = (const float*)d_in[2];
  const float* lin1_b = (const float*)d_in[3];
  const float* gat_W  = (const float*)d_in[4];
  const float* a_self = (const float*)d_in[5];
  const float* a_nei  = (const float*)d_in[6];
  const float* W_ih   = (const float*)d_in[7];
  const float* lin2_w = (const float*)d_in[9];
  const float* lin2_b = (const float*)d_in[10];

  float* A_pred = (float*)d_out;
  float* z_out  = A_pred + (size_t)NN_ * NN_;
  float* out_o  = z_out + (size_t)NN_ * OUT_;

  char* w = (char*)d_ws;
  u16* h_bf   = (u16*)w;                                 // 2 MB
  u16* g_bf   = (u16*)(w + (2u << 20));                  // 2 MB
  u16* h1_bf  = (u16*)(w + (4u << 20));                  // 2 MB
  u16* zb     = (u16*)(w + (6u << 20));                  // 1 MB
  u16* Wih_bf = (u16*)(w + (7u << 20));                  // 512 KB
  u16* WcT_bf = (u16*)(w + (7u << 20) + (512u << 10));   // 256 KB
  u16* l2w_bf = (u16*)(w + (7u << 20) + (768u << 10));   // 64 KB
  float* bcomb= (float*)(w + (7u << 20) + (832u << 10)); // 1 KB
  float* s    = (float*)(w + (7u << 20) + (896u << 10)); // 16 KB
  float* t    = (float*)(w + (7u << 20) + (960u << 10)); // 16 KB

  prep_kernel<<<dim3(33), dim3(256), 0, stream>>>(
      lin1_w, gat_W, lin1_b, WcT_bf, bcomb);
  hgemm_st_kernel<<<dim3(544), dim3(256), 0, stream>>>(
      x, WcT_bf, bcomb, a_self, a_nei, W_ih, lin2_w, h_bf, s, t, Wih_bf, l2w_bf);
  attn2_kernel<<<dim3(4096), dim3(256), 0, stream>>>(adj, h_bf, s, t, g_bf);
  gates_lstm_kernel<<<dim3(8, 32), dim3(256), 0, stream>>>(g_bf, Wih_bf, h1_bf);
  lin2f_kernel<<<dim3(256), dim3(256), 0, stream>>>(h1_bf, l2w_bf, lin2_b, out_o, z_out, zb);
  decode_kernel<<<dim3(32, 32), dim3(256), 0, stream>>>(zb, A_pred);
}